// Round 5
// baseline (191.377 us; speedup 1.0000x reference)
//
#include <hip/hip_runtime.h>

// ResNetVQC: 6 q3-layers of 32 three-qubit circuits + linear head.
// Each (layer,block,wire) expectation is an exact trilinear form; factorized as
//   z_w = sum_p v0[p] * ( T[w][p][.] . m[.] ),
//   m = (1, c1, s1, c2, s2, c1c2, c1s2, s1c2, s1s2),  v0 = (1, c0, s0)
// T (6*32*81 floats) depends only on thetas -> built by a tiny setup kernel.
//
// Main kernel: ONE THREAD OWNS ONE BATCH ROW (96 features) entirely in
// registers. The "fully" permutation between residual layers is a
// compile-time register permutation; residual adds are register adds.
// No barriers, no LDS in the main loop — only wave-uniform T s_loads
// (SGPR broadcast). 1024 blocks x 64 threads = 1024 waves = 1 wave/SIMD:
// all TLP traded for ILP (32 independent evals in flight per layer).

#define STRIDE 97

// ---------------- setup kernel: build T from thetas ----------------
// grid: 6 blocks (one per q3-layer), 256 threads: k = t>>3 (32 blocks), col = t&7
__global__ __launch_bounds__(256) void build_T(const float* __restrict__ thetas,
                                               float* __restrict__ T) {
  __shared__ float Ur[32][8][8];  // [k][col][amp]
  __shared__ float Ui[32][8][8];
  const int l = blockIdx.x;
  const int t = threadIdx.x;
  const int k = t >> 3;
  const int col = t & 7;

  float pr[8], pi[8];
#pragma unroll
  for (int j = 0; j < 8; ++j) { pr[j] = (j == col) ? 1.f : 0.f; pi[j] = 0.f; }

  const float* th = thetas + (size_t)(l * 32 + k) * 54;  // [d][w][3]
#pragma unroll
  for (int d = 0; d < 6; ++d) {
#pragma unroll
    for (int w = 0; w < 3; ++w) {
      float phi = th[(d * 3 + w) * 3 + 0];
      float tht = th[(d * 3 + w) * 3 + 1];
      float omg = th[(d * 3 + w) * 3 + 2];
      float st, ct, sp, cp, sm, cm;
      __sincosf(0.5f * tht, &st, &ct);
      __sincosf(0.5f * (phi + omg), &sp, &cp);
      __sincosf(0.5f * (phi - omg), &sm, &cm);
      float m00r =  cp * ct, m00i = -sp * ct;
      float m01r = -cm * st, m01i = -sm * st;
      float m10r =  cm * st, m10i = -sm * st;
      float m11r =  cp * ct, m11i =  sp * ct;
      const int s = 4 >> w;  // qubit0 = MSB
#pragma unroll
      for (int base = 0; base < 8; ++base) {
        if (base & s) continue;
        float ar = pr[base], ai = pi[base];
        float br = pr[base + s], bi = pi[base + s];
        pr[base]     = m00r * ar - m00i * ai + m01r * br - m01i * bi;
        pi[base]     = m00r * ai + m00i * ar + m01r * bi + m01i * br;
        pr[base + s] = m10r * ar - m10i * ai + m11r * br - m11i * bi;
        pi[base + s] = m10r * ai + m10i * ar + m11r * bi + m11i * br;
      }
    }
    const int r = (d & 1) + 1;  // CNOT ring range: 1,2,1,2,...
#pragma unroll
    for (int w = 0; w < 3; ++w) {
      const int cs = 4 >> w;
      const int ts = 4 >> ((w + r) % 3);
#pragma unroll
      for (int idx = 0; idx < 8; ++idx) {
        if (!(idx & cs) || (idx & ts)) continue;
        const int j2 = idx | ts;
        float tr = pr[idx]; pr[idx] = pr[j2]; pr[j2] = tr;
        float ti = pi[idx]; pi[idx] = pi[j2]; pi[j2] = ti;
      }
    }
  }
#pragma unroll
  for (int j = 0; j < 8; ++j) { Ur[k][col][j] = pr[j]; Ui[k][col][j] = pi[j]; }
  __syncthreads();

  if (col < 3) {
    const int w = col;  // wire
    float rem[8][8];
#pragma unroll
    for (int a = 0; a < 8; ++a) {
#pragma unroll
      for (int bb = 0; bb < 8; ++bb) {
        float acc = 0.f;
#pragma unroll
        for (int c = 0; c < 8; ++c) {
          float zs = ((c >> (2 - w)) & 1) ? -1.f : 1.f;
          acc += zs * (Ur[k][a][c] * Ur[k][bb][c] + Ui[k][a][c] * Ui[k][bb][c]);
        }
        rem[a][bb] = acc;
      }
    }
    const int   ga[3][2] = {{0, 1}, {0, 1}, {0, 1}};
    const int   gb[3][2] = {{0, 1}, {0, 1}, {1, 0}};
    const float gc[3][2] = {{0.5f, 0.5f}, {0.5f, -0.5f}, {0.5f, 0.5f}};
    // monomial index for (q,r): m = (1,c1,s1,c2,s2,c1c2,c1s2,s1c2,s1s2)
    const int MONO[3][3] = {{0, 3, 4}, {1, 5, 6}, {2, 7, 8}};
    float* To = T + ((size_t)(l * 32 + k) * 3 + w) * 27;
#pragma unroll
    for (int p = 0; p < 3; ++p) {
#pragma unroll
      for (int q = 0; q < 3; ++q) {
#pragma unroll
        for (int rr = 0; rr < 3; ++rr) {
          float acc = 0.f;
#pragma unroll
          for (int e0 = 0; e0 < 2; ++e0)
#pragma unroll
            for (int e1 = 0; e1 < 2; ++e1)
#pragma unroll
              for (int e2 = 0; e2 < 2; ++e2) {
                int a  = (ga[p][e0] << 2) | (ga[q][e1] << 1) | ga[rr][e2];
                int bb = (gb[p][e0] << 2) | (gb[q][e1] << 1) | gb[rr][e2];
                acc += gc[p][e0] * gc[q][e1] * gc[rr][e2] * rem[a][bb];
              }
          To[p * 9 + MONO[q][rr]] = acc;  // layout [w][p][mono]
        }
      }
    }
  }
}

// ---------------- main kernel ----------------
// Factorized trilinear eval: every inner fmac has exactly one scalar (T) operand.
template <int NW>
__device__ __forceinline__ void q3eval(float x0, float x1, float x2,
                                       const float* __restrict__ tb,
                                       float* __restrict__ zz) {
  float s0, c0, s1, c1, s2, c2;
  __sincosf(x0, &s0, &c0);
  __sincosf(x1, &s1, &c1);
  __sincosf(x2, &s2, &c2);
  float mm[9];
  mm[0] = 1.f; mm[1] = c1; mm[2] = s1; mm[3] = c2; mm[4] = s2;
  mm[5] = c1 * c2; mm[6] = c1 * s2; mm[7] = s1 * c2; mm[8] = s1 * s2;
#pragma unroll
  for (int w = 0; w < NW; ++w) {
    float P[3];
#pragma unroll
    for (int p = 0; p < 3; ++p) {
      const float* tt = tb + w * 27 + p * 9;
      float acc = tt[0];
#pragma unroll
      for (int i = 1; i < 9; ++i) acc = fmaf(tt[i], mm[i], acc);
      P[p] = acc;
    }
    zz[w] = fmaf(s0, P[2], fmaf(c0, P[1], P[0]));
  }
}

// 64 threads = 1 wave per block; thread t owns batch row b0+t fully in regs.
// __launch_bounds__(64,1): VGPR cap 512 -> no spill; 1 wave/SIMD by design.
__global__ __launch_bounds__(64, 1) void vqc_main(const float* __restrict__ x,
                                                  const float* __restrict__ T,
                                                  const float* __restrict__ wcls,
                                                  const float* __restrict__ bcls,
                                                  float* __restrict__ out) {
  __shared__ float smem[64 * STRIDE];  // 24832 B — x transpose staging only
  const int t = threadIdx.x;           // 0..63 = lane
  const int b0 = blockIdx.x * 64;

  // coalesced stage: 64 rows x 96 cols, float4 loads -> LDS rows (stride 97)
  const float4* xv = (const float4*)(x + (size_t)b0 * 96);
#pragma unroll
  for (int p = 0; p < 24; ++p) {
    int f = p * 64 + t;              // float4 index in the 64x96 tile
    float4 v = xv[f];
    int row = f / 24;
    int col = (f % 24) * 4;
    float* dst = &smem[row * STRIDE + col];
    dst[0] = v.x; dst[1] = v.y; dst[2] = v.z; dst[3] = v.w;
  }
  __syncthreads();

  // own row -> registers (static indices; 2-way bank alias only)
  float H[96];
#pragma unroll
  for (int i = 0; i < 96; ++i) H[i] = smem[t * STRIDE + i];

  float Hn[96];

  // layer 0 (stem): contiguous blocks, no residual
#pragma unroll
  for (int k = 0; k < 32; ++k) {
    float z[3];
    q3eval<3>(H[3 * k + 0], H[3 * k + 1], H[3 * k + 2], T + (size_t)k * 81, z);
    Hn[3 * k + 0] = z[0]; Hn[3 * k + 1] = z[1]; Hn[3 * k + 2] = z[2];
  }
#pragma unroll
  for (int i = 0; i < 96; ++i) H[i] = Hn[i];

  // layers 1..4: "fully" permutation = compile-time register permutation;
  // residual add in registers. Layer loop rolled (hot body ~fits I$).
  for (int l = 1; l < 5; ++l) {
    const float* Tl = T + (size_t)l * 2592;
#pragma unroll
    for (int k = 0; k < 32; ++k) {
      const int m0 = 3 * k, m1 = 3 * k + 1, m2 = 3 * k + 2;
      float z[3];
      q3eval<3>(H[3 * (m0 & 31) + (m0 >> 5)],
                H[3 * (m1 & 31) + (m1 >> 5)],
                H[3 * (m2 & 31) + (m2 >> 5)],
                Tl + (size_t)k * 81, z);
      Hn[3 * k + 0] = H[3 * k + 0] + z[0];
      Hn[3 * k + 1] = H[3 * k + 1] + z[1];
      Hn[3 * k + 2] = H[3 * k + 2] + z[2];
    }
#pragma unroll
    for (int i = 0; i < 96; ++i) H[i] = Hn[i];
  }

  // layer 5 (reduce, wire 0) fused with classifier
  float logits[10];
#pragma unroll
  for (int c = 0; c < 10; ++c) logits[c] = bcls[c];
  const float* T5 = T + (size_t)5 * 2592;
#pragma unroll
  for (int k = 0; k < 32; ++k) {
    float z[1];
    q3eval<1>(H[3 * k + 0], H[3 * k + 1], H[3 * k + 2], T5 + (size_t)k * 81, z);
#pragma unroll
    for (int c = 0; c < 10; ++c)
      logits[c] = fmaf(z[0], wcls[c * 32 + k], logits[c]);
  }

  float* op = out + (size_t)(b0 + t) * 10;
#pragma unroll
  for (int c = 0; c < 10; ++c) op[c] = logits[c];
}

extern "C" void kernel_launch(void* const* d_in, const int* in_sizes, int n_in,
                              void* d_out, int out_size, void* d_ws, size_t ws_size,
                              hipStream_t stream) {
  const float* x  = (const float*)d_in[0];   // (65536, 96) f32
  const float* th = (const float*)d_in[1];   // (6,32,6,3,3) f32
  const float* wc = (const float*)d_in[2];   // (10,32) f32
  const float* bc = (const float*)d_in[3];   // (10,) f32
  float* out = (float*)d_out;                // (65536,10) f32
  float* T = (float*)d_ws;                   // 6*32*81 = 15552 floats (62 KB)

  build_T<<<6, 256, 0, stream>>>(th, T);
  vqc_main<<<65536 / 64, 64, 0, stream>>>(x, T, wc, bc, out);
}

// Round 6
// 54.982 us; speedup vs baseline: 3.4807x; 3.4807x over previous
//
#include <hip/hip_runtime.h>

// ResNetVQC: 6 q3-layers of 32 three-qubit circuits + linear head.
// Each (layer,block,wire) expectation is an exact trilinear form; factorized as
//   z_w = sum_p v0[p] * ( T[w][p][.] . m[.] ),
//   m = (1, c1, s1, c2, s2, c1c2, c1s2, s1c2, s1s2),  v0 = (1, c0, s0)
// so every inner FMA reads exactly one scalar (T) operand -> no v_mov fill.
// T (6*32*81 floats) depends only on thetas -> built by a tiny setup kernel.
// Main kernel: 512 threads = 8 waves; lane = batch elem (64/block); each thread
// owns 4 k-blocks (k = ws*4 + kk). Single LDS buffer, read-all/barrier/write.

#define STRIDE 97

// ---------------- setup kernel: build T from thetas ----------------
// grid: 6 blocks (one per q3-layer), 256 threads: k = t>>3 (32 blocks), col = t&7
__global__ __launch_bounds__(256) void build_T(const float* __restrict__ thetas,
                                               float* __restrict__ T) {
  __shared__ float Ur[32][8][8];  // [k][col][amp]
  __shared__ float Ui[32][8][8];
  const int l = blockIdx.x;
  const int t = threadIdx.x;
  const int k = t >> 3;
  const int col = t & 7;

  float pr[8], pi[8];
#pragma unroll
  for (int j = 0; j < 8; ++j) { pr[j] = (j == col) ? 1.f : 0.f; pi[j] = 0.f; }

  const float* th = thetas + (size_t)(l * 32 + k) * 54;  // [d][w][3]
#pragma unroll
  for (int d = 0; d < 6; ++d) {
#pragma unroll
    for (int w = 0; w < 3; ++w) {
      float phi = th[(d * 3 + w) * 3 + 0];
      float tht = th[(d * 3 + w) * 3 + 1];
      float omg = th[(d * 3 + w) * 3 + 2];
      float st, ct, sp, cp, sm, cm;
      __sincosf(0.5f * tht, &st, &ct);
      __sincosf(0.5f * (phi + omg), &sp, &cp);
      __sincosf(0.5f * (phi - omg), &sm, &cm);
      float m00r =  cp * ct, m00i = -sp * ct;
      float m01r = -cm * st, m01i = -sm * st;
      float m10r =  cm * st, m10i = -sm * st;
      float m11r =  cp * ct, m11i =  sp * ct;
      const int s = 4 >> w;  // qubit0 = MSB
#pragma unroll
      for (int base = 0; base < 8; ++base) {
        if (base & s) continue;
        float ar = pr[base], ai = pi[base];
        float br = pr[base + s], bi = pi[base + s];
        pr[base]     = m00r * ar - m00i * ai + m01r * br - m01i * bi;
        pi[base]     = m00r * ai + m00i * ar + m01r * bi + m01i * br;
        pr[base + s] = m10r * ar - m10i * ai + m11r * br - m11i * bi;
        pi[base + s] = m10r * ai + m10i * ar + m11r * bi + m11i * br;
      }
    }
    const int r = (d & 1) + 1;  // CNOT ring range: 1,2,1,2,...
#pragma unroll
    for (int w = 0; w < 3; ++w) {
      const int cs = 4 >> w;
      const int ts = 4 >> ((w + r) % 3);
#pragma unroll
      for (int idx = 0; idx < 8; ++idx) {
        if (!(idx & cs) || (idx & ts)) continue;
        const int j2 = idx | ts;
        float tr = pr[idx]; pr[idx] = pr[j2]; pr[j2] = tr;
        float ti = pi[idx]; pi[idx] = pi[j2]; pi[j2] = ti;
      }
    }
  }
#pragma unroll
  for (int j = 0; j < 8; ++j) { Ur[k][col][j] = pr[j]; Ui[k][col][j] = pi[j]; }
  __syncthreads();

  if (col < 3) {
    const int w = col;  // wire
    float rem[8][8];
#pragma unroll
    for (int a = 0; a < 8; ++a) {
#pragma unroll
      for (int bb = 0; bb < 8; ++bb) {
        float acc = 0.f;
#pragma unroll
        for (int c = 0; c < 8; ++c) {
          float zs = ((c >> (2 - w)) & 1) ? -1.f : 1.f;
          acc += zs * (Ur[k][a][c] * Ur[k][bb][c] + Ui[k][a][c] * Ui[k][bb][c]);
        }
        rem[a][bb] = acc;
      }
    }
    const int   ga[3][2] = {{0, 1}, {0, 1}, {0, 1}};
    const int   gb[3][2] = {{0, 1}, {0, 1}, {1, 0}};
    const float gc[3][2] = {{0.5f, 0.5f}, {0.5f, -0.5f}, {0.5f, 0.5f}};
    // monomial index for (q,r): m = (1,c1,s1,c2,s2,c1c2,c1s2,s1c2,s1s2)
    const int MONO[3][3] = {{0, 3, 4}, {1, 5, 6}, {2, 7, 8}};
    float* To = T + ((size_t)(l * 32 + k) * 3 + w) * 27;
#pragma unroll
    for (int p = 0; p < 3; ++p) {
#pragma unroll
      for (int q = 0; q < 3; ++q) {
#pragma unroll
        for (int rr = 0; rr < 3; ++rr) {
          float acc = 0.f;
#pragma unroll
          for (int e0 = 0; e0 < 2; ++e0)
#pragma unroll
            for (int e1 = 0; e1 < 2; ++e1)
#pragma unroll
              for (int e2 = 0; e2 < 2; ++e2) {
                int a  = (ga[p][e0] << 2) | (ga[q][e1] << 1) | ga[rr][e2];
                int bb = (gb[p][e0] << 2) | (gb[q][e1] << 1) | gb[rr][e2];
                acc += gc[p][e0] * gc[q][e1] * gc[rr][e2] * rem[a][bb];
              }
          To[p * 9 + MONO[q][rr]] = acc;  // layout [w][p][mono]
        }
      }
    }
  }
}

// ---------------- main kernel ----------------
// Factorized trilinear eval: 4 shared muls + 27 fmac (one scalar operand each)
// + 2 fma per wire.
template <int NW>
__device__ __forceinline__ void q3eval(float x0, float x1, float x2,
                                       const float* __restrict__ tb,
                                       float* __restrict__ zz) {
  float s0, c0, s1, c1, s2, c2;
  __sincosf(x0, &s0, &c0);
  __sincosf(x1, &s1, &c1);
  __sincosf(x2, &s2, &c2);
  float mm[9];
  mm[0] = 1.f; mm[1] = c1; mm[2] = s1; mm[3] = c2; mm[4] = s2;
  mm[5] = c1 * c2; mm[6] = c1 * s2; mm[7] = s1 * c2; mm[8] = s1 * s2;
#pragma unroll
  for (int w = 0; w < NW; ++w) {
    float P[3];
#pragma unroll
    for (int p = 0; p < 3; ++p) {
      const float* tt = tb + w * 27 + p * 9;
      float acc = tt[0];
#pragma unroll
      for (int i = 1; i < 9; ++i) acc = fmaf(tt[i], mm[i], acc);
      P[p] = acc;
    }
    zz[w] = fmaf(s0, P[2], fmaf(c0, P[1], P[0]));
  }
}

// block = 512 threads = 8 waves; lane b = batch elem (64/block); wave ws owns
// k-blocks {4ws .. 4ws+3}. One LDS buffer [64][97]; read-all -> B -> write -> B.
__global__ __launch_bounds__(512, 8) void vqc_main(const float* __restrict__ x,
                                                   const float* __restrict__ T,
                                                   const float* __restrict__ wcls,
                                                   const float* __restrict__ bcls,
                                                   float* __restrict__ out) {
  __shared__ float buf[64 * STRIDE];  // 24832 B
  const int t = threadIdx.x;
  const int b0 = blockIdx.x * 64;

  // stage x (coalesced float4 reads) into buf
  const float4* xv = (const float4*)(x + (size_t)b0 * 96);
#pragma unroll
  for (int i = 0; i < 3; ++i) {
    float4 v = xv[t + i * 512];
    int idx = (t + i * 512) * 4;
    int row = idx / 96, col = idx % 96;
    float* p = &buf[row * STRIDE + col];
    p[0] = v.x; p[1] = v.y; p[2] = v.z; p[3] = v.w;
  }

  const int b = t & 63;                                   // batch within block
  const int ws = __builtin_amdgcn_readfirstlane(t >> 6);  // wave id 0..7 (scalar)

  // "fully" permutation gather indices: inp[3k+j] = H[3*((3k+j)%32) + (3k+j)/32]
  int gf[4][3];
#pragma unroll
  for (int kk = 0; kk < 4; ++kk) {
    int k = ws * 4 + kk;
#pragma unroll
    for (int j = 0; j < 3; ++j) {
      int m = 3 * k + j;
      gf[kk][j] = 3 * (m & 31) + (m >> 5);
    }
  }
  __syncthreads();

  float h[4][3];
  // layer 0 (stem): natural block order (own positions), no residual
#pragma unroll
  for (int kk = 0; kk < 4; ++kk) {
    int k = ws * 4 + kk;
    float z[3];
    q3eval<3>(buf[b * STRIDE + 3 * k + 0], buf[b * STRIDE + 3 * k + 1],
              buf[b * STRIDE + 3 * k + 2], T + (size_t)k * 81, z);
#pragma unroll
    for (int j = 0; j < 3; ++j) {
      h[kk][j] = z[j];
      buf[b * STRIDE + 3 * k + j] = z[j];  // own positions: no race
    }
  }
  __syncthreads();

  // layers 1..4: permuted gather, residual add (residual = own regs)
  for (int l = 1; l < 5; ++l) {
    const float* Tl = T + (size_t)l * 32 * 81;
    float xin[4][3];
#pragma unroll
    for (int kk = 0; kk < 4; ++kk)
#pragma unroll
      for (int j = 0; j < 3; ++j) xin[kk][j] = buf[b * STRIDE + gf[kk][j]];
    __syncthreads();  // all reads of H_{l-1} done
#pragma unroll
    for (int kk = 0; kk < 4; ++kk) {
      int k = ws * 4 + kk;
      float z[3];
      q3eval<3>(xin[kk][0], xin[kk][1], xin[kk][2], Tl + k * 81, z);
#pragma unroll
      for (int j = 0; j < 3; ++j) h[kk][j] += z[j];
      if (l < 4) {
#pragma unroll
        for (int j = 0; j < 3; ++j) buf[b * STRIDE + 3 * k + j] = h[kk][j];
      }
    }
    if (l < 4) __syncthreads();  // writes of H_l visible before next gathers
  }

  // layer 5 (reduce): input = own registers; wire 0 only; stash z into buf[b][k]
#pragma unroll
  for (int kk = 0; kk < 4; ++kk) {
    int k = ws * 4 + kk;
    float z[1];
    q3eval<1>(h[kk][0], h[kk][1], h[kk][2], T + (size_t)(5 * 32 + k) * 81, z);
    buf[b * STRIDE + k] = z[0];  // safe: layer-4 gathers done at last barrier
  }
  __syncthreads();

  // classifier: out[b][c] = sum_k z[b][k] * wcls[c][k] + bcls[c]
  // 640 work items on 512 threads -> grid-stride
  for (int idx = t; idx < 640; idx += 512) {
    int bb = idx / 10, c = idx % 10;
    float acc = bcls[c];
#pragma unroll
    for (int k = 0; k < 32; ++k)
      acc = fmaf(buf[bb * STRIDE + k], wcls[c * 32 + k], acc);
    out[(size_t)(b0 + bb) * 10 + c] = acc;
  }
}

extern "C" void kernel_launch(void* const* d_in, const int* in_sizes, int n_in,
                              void* d_out, int out_size, void* d_ws, size_t ws_size,
                              hipStream_t stream) {
  const float* x  = (const float*)d_in[0];   // (65536, 96) f32
  const float* th = (const float*)d_in[1];   // (6,32,6,3,3) f32
  const float* wc = (const float*)d_in[2];   // (10,32) f32
  const float* bc = (const float*)d_in[3];   // (10,) f32
  float* out = (float*)d_out;                // (65536,10) f32
  float* T = (float*)d_ws;                   // 6*32*81 = 15552 floats (62 KB)

  build_T<<<6, 256, 0, stream>>>(th, T);
  vqc_main<<<65536 / 64, 512, 0, stream>>>(x, T, wc, bc, out);
}

// Round 7
// 52.995 us; speedup vs baseline: 3.6112x; 1.0375x over previous
//
#include <hip/hip_runtime.h>

// ResNetVQC: 6 q3-layers of 32 three-qubit circuits + linear head.
// Each (layer,block,wire) expectation is an exact trilinear form; factorized as
//   z_w = sum_p v0[p] * ( T[w][p][.] . m[.] ),
//   m = (1, c1, s1, c2, s2, c1c2, c1s2, s1c2, s1s2),  v0 = (1, c0, s0)
// T depends only on thetas -> built by a tiny setup kernel, stored BOTH as
// f32 (layer 5 + fallback) and as f16 pairs for v_dot2_f32_f16 (layers 0-4:
// 45 dot2 replace 81 fmac; f16 x f16 products are exact in the f32 accum, so
// only input quantization error ~5e-4 enters).
// Main kernel: 512 threads = 8 waves; lane = batch row (64/block); wave ws owns
// k in {4ws..4ws+3}. Single LDS buffer [64][97], read-all/barrier/write.

#define STRIDE 97

typedef _Float16 hf2 __attribute__((ext_vector_type(2)));

#if __has_builtin(__builtin_amdgcn_fdot2)
#define HAVE_FDOT2 1
#else
#define HAVE_FDOT2 0
#endif

// ---------------- setup kernel: build T from thetas ----------------
// grid: 6 blocks (one per q3-layer), 256 threads: k = t>>3 (32 blocks), col = t&7
__global__ __launch_bounds__(256) void build_T(const float* __restrict__ thetas,
                                               float* __restrict__ T,
                                               hf2* __restrict__ Th) {
  __shared__ float Ur[32][8][8];  // [k][col][amp]
  __shared__ float Ui[32][8][8];
  const int l = blockIdx.x;
  const int t = threadIdx.x;
  const int k = t >> 3;
  const int col = t & 7;

  float pr[8], pi[8];
#pragma unroll
  for (int j = 0; j < 8; ++j) { pr[j] = (j == col) ? 1.f : 0.f; pi[j] = 0.f; }

  const float* th = thetas + (size_t)(l * 32 + k) * 54;  // [d][w][3]
#pragma unroll
  for (int d = 0; d < 6; ++d) {
#pragma unroll
    for (int w = 0; w < 3; ++w) {
      float phi = th[(d * 3 + w) * 3 + 0];
      float tht = th[(d * 3 + w) * 3 + 1];
      float omg = th[(d * 3 + w) * 3 + 2];
      float st, ct, sp, cp, sm, cm;
      __sincosf(0.5f * tht, &st, &ct);
      __sincosf(0.5f * (phi + omg), &sp, &cp);
      __sincosf(0.5f * (phi - omg), &sm, &cm);
      float m00r =  cp * ct, m00i = -sp * ct;
      float m01r = -cm * st, m01i = -sm * st;
      float m10r =  cm * st, m10i = -sm * st;
      float m11r =  cp * ct, m11i =  sp * ct;
      const int s = 4 >> w;  // qubit0 = MSB
#pragma unroll
      for (int base = 0; base < 8; ++base) {
        if (base & s) continue;
        float ar = pr[base], ai = pi[base];
        float br = pr[base + s], bi = pi[base + s];
        pr[base]     = m00r * ar - m00i * ai + m01r * br - m01i * bi;
        pi[base]     = m00r * ai + m00i * ar + m01r * bi + m01i * br;
        pr[base + s] = m10r * ar - m10i * ai + m11r * br - m11i * bi;
        pi[base + s] = m10r * ai + m10i * ar + m11r * bi + m11i * br;
      }
    }
    const int r = (d & 1) + 1;  // CNOT ring range: 1,2,1,2,...
#pragma unroll
    for (int w = 0; w < 3; ++w) {
      const int cs = 4 >> w;
      const int ts = 4 >> ((w + r) % 3);
#pragma unroll
      for (int idx = 0; idx < 8; ++idx) {
        if (!(idx & cs) || (idx & ts)) continue;
        const int j2 = idx | ts;
        float tr = pr[idx]; pr[idx] = pr[j2]; pr[j2] = tr;
        float ti = pi[idx]; pi[idx] = pi[j2]; pi[j2] = ti;
      }
    }
  }
#pragma unroll
  for (int j = 0; j < 8; ++j) { Ur[k][col][j] = pr[j]; Ui[k][col][j] = pi[j]; }
  __syncthreads();

  if (col < 3) {
    const int w = col;  // wire
    float rem[8][8];
#pragma unroll
    for (int a = 0; a < 8; ++a) {
#pragma unroll
      for (int bb = 0; bb < 8; ++bb) {
        float acc = 0.f;
#pragma unroll
        for (int c = 0; c < 8; ++c) {
          float zs = ((c >> (2 - w)) & 1) ? -1.f : 1.f;
          acc += zs * (Ur[k][a][c] * Ur[k][bb][c] + Ui[k][a][c] * Ui[k][bb][c]);
        }
        rem[a][bb] = acc;
      }
    }
    const int   ga[3][2] = {{0, 1}, {0, 1}, {0, 1}};
    const int   gb[3][2] = {{0, 1}, {0, 1}, {1, 0}};
    const float gc[3][2] = {{0.5f, 0.5f}, {0.5f, -0.5f}, {0.5f, 0.5f}};
    // monomial index for (q,r): m = (1,c1,s1,c2,s2,c1c2,c1s2,s1c2,s1s2)
    const int MONO[3][3] = {{0, 3, 4}, {1, 5, 6}, {2, 7, 8}};
    float tv[27];
#pragma unroll
    for (int p = 0; p < 3; ++p) {
#pragma unroll
      for (int q = 0; q < 3; ++q) {
#pragma unroll
        for (int rr = 0; rr < 3; ++rr) {
          float acc = 0.f;
#pragma unroll
          for (int e0 = 0; e0 < 2; ++e0)
#pragma unroll
            for (int e1 = 0; e1 < 2; ++e1)
#pragma unroll
              for (int e2 = 0; e2 < 2; ++e2) {
                int a  = (ga[p][e0] << 2) | (ga[q][e1] << 1) | ga[rr][e2];
                int bb = (gb[p][e0] << 2) | (gb[q][e1] << 1) | gb[rr][e2];
                acc += gc[p][e0] * gc[q][e1] * gc[rr][e2] * rem[a][bb];
              }
          tv[p * 9 + MONO[q][rr]] = acc;
        }
      }
    }
    // f32 table: layout [l][k][w][p][mono]
    float* To = T + ((size_t)(l * 32 + k) * 3 + w) * 27;
#pragma unroll
    for (int i = 0; i < 27; ++i) To[i] = tv[i];
    // f16-pair table for dot2: layout [l][k][w][p][5 pairs]
    hf2* Tp = Th + (((size_t)(l * 32 + k) * 3 + w) * 3) * 5;
#pragma unroll
    for (int p = 0; p < 3; ++p) {
#pragma unroll
      for (int d = 0; d < 4; ++d) {
        hf2 v = {(_Float16)tv[p * 9 + 2 * d], (_Float16)tv[p * 9 + 2 * d + 1]};
        Tp[p * 5 + d] = v;
      }
      hf2 v4 = {(_Float16)tv[p * 9 + 8], (_Float16)0.f};
      Tp[p * 5 + 4] = v4;
    }
  }
}

// ---------------- main kernel evals ----------------
// f32 path (layer 5 / fallback): factorized trilinear, 27 fmac per wire.
template <int NW>
__device__ __forceinline__ void q3eval(float x0, float x1, float x2,
                                       const float* __restrict__ tb,
                                       float* __restrict__ zz) {
  float s0, c0, s1, c1, s2, c2;
  __sincosf(x0, &s0, &c0);
  __sincosf(x1, &s1, &c1);
  __sincosf(x2, &s2, &c2);
  float mm[9];
  mm[0] = 1.f; mm[1] = c1; mm[2] = s1; mm[3] = c2; mm[4] = s2;
  mm[5] = c1 * c2; mm[6] = c1 * s2; mm[7] = s1 * c2; mm[8] = s1 * s2;
#pragma unroll
  for (int w = 0; w < NW; ++w) {
    float P[3];
#pragma unroll
    for (int p = 0; p < 3; ++p) {
      const float* tt = tb + w * 27 + p * 9;
      float acc = tt[0];
#pragma unroll
      for (int i = 1; i < 9; ++i) acc = fmaf(tt[i], mm[i], acc);
      P[p] = acc;
    }
    zz[w] = fmaf(s0, P[2], fmaf(c0, P[1], P[0]));
  }
}

// dot2 path (layers 0-4): 45 v_dot2_f32_f16 replace 81 fmac; f32 accumulate.
__device__ __forceinline__ void q3eval_h(float x0, float x1, float x2,
                                         const hf2* __restrict__ th,
                                         float* __restrict__ zz) {
#if HAVE_FDOT2
  float s0, c0, s1, c1, s2, c2;
  __sincosf(x0, &s0, &c0);
  __sincosf(x1, &s1, &c1);
  __sincosf(x2, &s2, &c2);
  float m5 = c1 * c2, m6 = c1 * s2, m7 = s1 * c2, m8 = s1 * s2;
  hf2 M0 = {(_Float16)1.0f, (_Float16)c1};
  hf2 M1 = {(_Float16)s1,   (_Float16)c2};
  hf2 M2 = {(_Float16)s2,   (_Float16)m5};
  hf2 M3 = {(_Float16)m6,   (_Float16)m7};
  hf2 M4 = {(_Float16)m8,   (_Float16)0.0f};
#pragma unroll
  for (int w = 0; w < 3; ++w) {
    float P[3];
#pragma unroll
    for (int p = 0; p < 3; ++p) {
      const hf2* tt = th + (w * 3 + p) * 5;
      float acc = __builtin_amdgcn_fdot2(tt[0], M0, 0.0f, false);
      acc = __builtin_amdgcn_fdot2(tt[1], M1, acc, false);
      acc = __builtin_amdgcn_fdot2(tt[2], M2, acc, false);
      acc = __builtin_amdgcn_fdot2(tt[3], M3, acc, false);
      acc = __builtin_amdgcn_fdot2(tt[4], M4, acc, false);
      P[p] = acc;
    }
    zz[w] = fmaf(s0, P[2], fmaf(c0, P[1], P[0]));
  }
#else
  (void)th;
  // fallback never used when fdot2 exists; caller passes matching f32 table
  zz[0] = zz[1] = zz[2] = 0.f;
#endif
}

// block = 512 threads = 8 waves; lane b = batch elem (64/block); wave ws owns
// k-blocks {4ws .. 4ws+3}. One LDS buffer [64][97]; read-all -> B -> write -> B.
__global__ __launch_bounds__(512, 8) void vqc_main(const float* __restrict__ x,
                                                   const float* __restrict__ T,
                                                   const hf2* __restrict__ Th,
                                                   const float* __restrict__ wcls,
                                                   const float* __restrict__ bcls,
                                                   float* __restrict__ out) {
  __shared__ float buf[64 * STRIDE];  // 24832 B
  const int t = threadIdx.x;
  const int b0 = blockIdx.x * 64;

  // stage x (coalesced float4 reads) into buf
  const float4* xv = (const float4*)(x + (size_t)b0 * 96);
#pragma unroll
  for (int i = 0; i < 3; ++i) {
    float4 v = xv[t + i * 512];
    int idx = (t + i * 512) * 4;
    int row = idx / 96, col = idx % 96;
    float* p = &buf[row * STRIDE + col];
    p[0] = v.x; p[1] = v.y; p[2] = v.z; p[3] = v.w;
  }

  const int b = t & 63;                                   // batch within block
  const int ws = __builtin_amdgcn_readfirstlane(t >> 6);  // wave id 0..7 (scalar)

  // "fully" permutation gather indices: inp[3k+j] = H[3*((3k+j)%32) + (3k+j)/32]
  int gf[4][3];
#pragma unroll
  for (int kk = 0; kk < 4; ++kk) {
    int k = ws * 4 + kk;
#pragma unroll
    for (int j = 0; j < 3; ++j) {
      int m = 3 * k + j;
      gf[kk][j] = 3 * (m & 31) + (m >> 5);
    }
  }
  __syncthreads();

  float h[4][3];
  // layer 0 (stem): natural block order (own positions), no residual
#pragma unroll
  for (int kk = 0; kk < 4; ++kk) {
    int k = ws * 4 + kk;
    float z[3];
#if HAVE_FDOT2
    q3eval_h(buf[b * STRIDE + 3 * k + 0], buf[b * STRIDE + 3 * k + 1],
             buf[b * STRIDE + 3 * k + 2], Th + (size_t)k * 45, z);
#else
    q3eval<3>(buf[b * STRIDE + 3 * k + 0], buf[b * STRIDE + 3 * k + 1],
              buf[b * STRIDE + 3 * k + 2], T + (size_t)k * 81, z);
#endif
#pragma unroll
    for (int j = 0; j < 3; ++j) {
      h[kk][j] = z[j];
      buf[b * STRIDE + 3 * k + j] = z[j];  // own positions: no race
    }
  }
  __syncthreads();

  // layers 1..4: permuted gather, residual add (residual = own regs)
  for (int l = 1; l < 5; ++l) {
    float xin[4][3];
#pragma unroll
    for (int kk = 0; kk < 4; ++kk)
#pragma unroll
      for (int j = 0; j < 3; ++j) xin[kk][j] = buf[b * STRIDE + gf[kk][j]];
    __syncthreads();  // all reads of H_{l-1} done
#pragma unroll
    for (int kk = 0; kk < 4; ++kk) {
      int k = ws * 4 + kk;
      float z[3];
#if HAVE_FDOT2
      q3eval_h(xin[kk][0], xin[kk][1], xin[kk][2],
               Th + (size_t)(l * 32 + k) * 45, z);
#else
      q3eval<3>(xin[kk][0], xin[kk][1], xin[kk][2],
                T + (size_t)(l * 32 + k) * 81, z);
#endif
#pragma unroll
      for (int j = 0; j < 3; ++j) h[kk][j] += z[j];
      if (l < 4) {
#pragma unroll
        for (int j = 0; j < 3; ++j) buf[b * STRIDE + 3 * k + j] = h[kk][j];
      }
    }
    if (l < 4) __syncthreads();  // writes of H_l visible before next gathers
  }

  // layer 5 (reduce): input = own registers; wire 0 only; f32 path for accuracy
#pragma unroll
  for (int kk = 0; kk < 4; ++kk) {
    int k = ws * 4 + kk;
    float z[1];
    q3eval<1>(h[kk][0], h[kk][1], h[kk][2], T + (size_t)(5 * 32 + k) * 81, z);
    buf[b * STRIDE + k] = z[0];  // safe: layer-4 gathers done at last barrier
  }
  __syncthreads();

  // classifier: out[b][c] = sum_k z[b][k] * wcls[c][k] + bcls[c]
  for (int idx = t; idx < 640; idx += 512) {
    int bb = idx / 10, c = idx % 10;
    float acc = bcls[c];
#pragma unroll
    for (int k = 0; k < 32; ++k)
      acc = fmaf(buf[bb * STRIDE + k], wcls[c * 32 + k], acc);
    out[(size_t)(b0 + bb) * 10 + c] = acc;
  }
}

extern "C" void kernel_launch(void* const* d_in, const int* in_sizes, int n_in,
                              void* d_out, int out_size, void* d_ws, size_t ws_size,
                              hipStream_t stream) {
  const float* x  = (const float*)d_in[0];   // (65536, 96) f32
  const float* th = (const float*)d_in[1];   // (6,32,6,3,3) f32
  const float* wc = (const float*)d_in[2];   // (10,32) f32
  const float* bc = (const float*)d_in[3];   // (10,) f32
  float* out = (float*)d_out;                // (65536,10) f32
  float* T = (float*)d_ws;                   // 6*32*81 = 15552 f32 (62 KB)
  hf2* Th = (hf2*)(T + 15552);               // 6*32*45 = 8640 hf2 (34.6 KB)

  build_T<<<6, 256, 0, stream>>>(th, T, Th);
  vqc_main<<<65536 / 64, 512, 0, stream>>>(x, T, Th, wc, bc, out);
}

// Round 9
// 51.773 us; speedup vs baseline: 3.6965x; 1.0236x over previous
//
#include <hip/hip_runtime.h>

// ResNetVQC: 6 q3-layers of 32 three-qubit circuits + linear head.
// Each (layer,block,wire) expectation is an exact trilinear form; factorized as
//   z_w = sum_p v0[p] * ( T[w][p][.] . m[.] ),
//   m = (1, c1, s1, c2, s2, c1c2, c1s2, s1c2, s1s2),  v0 = (1, c0, s0)
// T depends only on thetas -> built by a tiny setup kernel, stored BOTH as
// f32 (layer 5) and as f16 pairs for v_dot2_f32_f16 (layers 0-4).
//
// Round-8/9 changes:
//  * native hw sincos (__sinf/__cosf -> v_sin/v_cos, revolutions): replaces
//    the accurate OCML __sincosf (~30 instrs) with 2 instrs each.
//  * consumer-order LDS layout: writer (k',j') stores slot 32j'+k', so every
//    reader's 12 gather inputs are the contiguous slots 12ws..12ws+11
//    (slot 3k+j holds H[3*((3k+j)%32) + (3k+j)/32], the "fully" permutation).
//    12 scattered reads + 12 writes -> 6 read2 + 6 write2 per thread-layer.

#define STRIDE 97

typedef _Float16 hf2 __attribute__((ext_vector_type(2)));

#if __has_builtin(__builtin_amdgcn_fdot2)
#define HAVE_FDOT2 1
#else
#define HAVE_FDOT2 0
#endif

// ---------------- setup kernel: build T from thetas ----------------
// grid: 6 blocks (one per q3-layer), 256 threads: k = t>>3 (32 blocks), col = t&7
__global__ __launch_bounds__(256) void build_T(const float* __restrict__ thetas,
                                               float* __restrict__ T,
                                               hf2* __restrict__ Th) {
  __shared__ float Ur[32][8][8];  // [k][col][amp]
  __shared__ float Ui[32][8][8];
  const int l = blockIdx.x;
  const int t = threadIdx.x;
  const int k = t >> 3;
  const int col = t & 7;

  float pr[8], pi[8];
#pragma unroll
  for (int j = 0; j < 8; ++j) { pr[j] = (j == col) ? 1.f : 0.f; pi[j] = 0.f; }

  const float* th = thetas + (size_t)(l * 32 + k) * 54;  // [d][w][3]
#pragma unroll
  for (int d = 0; d < 6; ++d) {
#pragma unroll
    for (int w = 0; w < 3; ++w) {
      float phi = th[(d * 3 + w) * 3 + 0];
      float tht = th[(d * 3 + w) * 3 + 1];
      float omg = th[(d * 3 + w) * 3 + 2];
      float st, ct, sp, cp, sm, cm;
      __sincosf(0.5f * tht, &st, &ct);
      __sincosf(0.5f * (phi + omg), &sp, &cp);
      __sincosf(0.5f * (phi - omg), &sm, &cm);
      float m00r =  cp * ct, m00i = -sp * ct;
      float m01r = -cm * st, m01i = -sm * st;
      float m10r =  cm * st, m10i = -sm * st;
      float m11r =  cp * ct, m11i =  sp * ct;
      const int s = 4 >> w;  // qubit0 = MSB
#pragma unroll
      for (int base = 0; base < 8; ++base) {
        if (base & s) continue;
        float ar = pr[base], ai = pi[base];
        float br = pr[base + s], bi = pi[base + s];
        pr[base]     = m00r * ar - m00i * ai + m01r * br - m01i * bi;
        pi[base]     = m00r * ai + m00i * ar + m01r * bi + m01i * br;
        pr[base + s] = m10r * ar - m10i * ai + m11r * br - m11i * bi;
        pi[base + s] = m10r * ai + m10i * ar + m11r * bi + m11i * br;
      }
    }
    const int r = (d & 1) + 1;  // CNOT ring range: 1,2,1,2,...
#pragma unroll
    for (int w = 0; w < 3; ++w) {
      const int cs = 4 >> w;
      const int ts = 4 >> ((w + r) % 3);
#pragma unroll
      for (int idx = 0; idx < 8; ++idx) {
        if (!(idx & cs) || (idx & ts)) continue;
        const int j2 = idx | ts;
        float tr = pr[idx]; pr[idx] = pr[j2]; pr[j2] = tr;
        float ti = pi[idx]; pi[idx] = pi[j2]; pi[j2] = ti;
      }
    }
  }
#pragma unroll
  for (int j = 0; j < 8; ++j) { Ur[k][col][j] = pr[j]; Ui[k][col][j] = pi[j]; }
  __syncthreads();

  if (col < 3) {
    const int w = col;  // wire
    float rem[8][8];
#pragma unroll
    for (int a = 0; a < 8; ++a) {
#pragma unroll
      for (int bb = 0; bb < 8; ++bb) {
        float acc = 0.f;
#pragma unroll
        for (int c = 0; c < 8; ++c) {
          float zs = ((c >> (2 - w)) & 1) ? -1.f : 1.f;
          acc += zs * (Ur[k][a][c] * Ur[k][bb][c] + Ui[k][a][c] * Ui[k][bb][c]);
        }
        rem[a][bb] = acc;
      }
    }
    const int   ga[3][2] = {{0, 1}, {0, 1}, {0, 1}};
    const int   gb[3][2] = {{0, 1}, {0, 1}, {1, 0}};
    const float gc[3][2] = {{0.5f, 0.5f}, {0.5f, -0.5f}, {0.5f, 0.5f}};
    // monomial index for (q,r): m = (1,c1,s1,c2,s2,c1c2,c1s2,s1c2,s1s2)
    const int MONO[3][3] = {{0, 3, 4}, {1, 5, 6}, {2, 7, 8}};
    float tv[27];
#pragma unroll
    for (int p = 0; p < 3; ++p) {
#pragma unroll
      for (int q = 0; q < 3; ++q) {
#pragma unroll
        for (int rr = 0; rr < 3; ++rr) {
          float acc = 0.f;
#pragma unroll
          for (int e0 = 0; e0 < 2; ++e0)
#pragma unroll
            for (int e1 = 0; e1 < 2; ++e1)
#pragma unroll
              for (int e2 = 0; e2 < 2; ++e2) {
                int a  = (ga[p][e0] << 2) | (ga[q][e1] << 1) | ga[rr][e2];
                int bb = (gb[p][e0] << 2) | (gb[q][e1] << 1) | gb[rr][e2];
                acc += gc[p][e0] * gc[q][e1] * gc[rr][e2] * rem[a][bb];
              }
          tv[p * 9 + MONO[q][rr]] = acc;
        }
      }
    }
    // f32 table: layout [l][k][w][p][mono]
    float* To = T + ((size_t)(l * 32 + k) * 3 + w) * 27;
#pragma unroll
    for (int i = 0; i < 27; ++i) To[i] = tv[i];
    // f16-pair table for dot2: layout [l][k][w][p][5 pairs]
    hf2* Tp = Th + (((size_t)(l * 32 + k) * 3 + w) * 3) * 5;
#pragma unroll
    for (int p = 0; p < 3; ++p) {
#pragma unroll
      for (int d = 0; d < 4; ++d) {
        hf2 v = {(_Float16)tv[p * 9 + 2 * d], (_Float16)tv[p * 9 + 2 * d + 1]};
        Tp[p * 5 + d] = v;
      }
      hf2 v4 = {(_Float16)tv[p * 9 + 8], (_Float16)0.f};
      Tp[p * 5 + 4] = v4;
    }
  }
}

// ---------------- main kernel evals ----------------
// native hw sincos: v_sin/v_cos take revolutions; |x| <~ 10 rad << 256 rev
// domain, so a single multiply is the whole range reduction. err ~1e-5.
__device__ __forceinline__ void fast_sincos(float x, float& s, float& c) {
  s = __sinf(x);
  c = __cosf(x);
}

// dot2 path (layers 0-4): 45 v_dot2_f32_f16; f32 accumulate.
__device__ __forceinline__ void q3eval_h(float s0, float c0, float s1, float c1,
                                         float s2, float c2,
                                         const hf2* __restrict__ th,
                                         float* __restrict__ zz) {
#if HAVE_FDOT2
  float m5 = c1 * c2, m6 = c1 * s2, m7 = s1 * c2, m8 = s1 * s2;
  hf2 M0 = {(_Float16)1.0f, (_Float16)c1};
  hf2 M1 = {(_Float16)s1,   (_Float16)c2};
  hf2 M2 = {(_Float16)s2,   (_Float16)m5};
  hf2 M3 = {(_Float16)m6,   (_Float16)m7};
  hf2 M4 = {(_Float16)m8,   (_Float16)0.0f};
#pragma unroll
  for (int w = 0; w < 3; ++w) {
    float P[3];
#pragma unroll
    for (int p = 0; p < 3; ++p) {
      const hf2* tt = th + (w * 3 + p) * 5;
      float acc = __builtin_amdgcn_fdot2(tt[0], M0, 0.0f, false);
      acc = __builtin_amdgcn_fdot2(tt[1], M1, acc, false);
      acc = __builtin_amdgcn_fdot2(tt[2], M2, acc, false);
      acc = __builtin_amdgcn_fdot2(tt[3], M3, acc, false);
      acc = __builtin_amdgcn_fdot2(tt[4], M4, acc, false);
      P[p] = acc;
    }
    zz[w] = fmaf(s0, P[2], fmaf(c0, P[1], P[0]));
  }
#else
  (void)th; (void)s1; (void)c2; (void)s2;
  zz[0] = zz[1] = zz[2] = 0.f;
#endif
}

// f32 path (layer 5, wire 0 only): factorized trilinear, 27 fmac.
__device__ __forceinline__ float q3eval1_f(float s0, float c0, float s1, float c1,
                                           float s2, float c2,
                                           const float* __restrict__ tb) {
  float mm[9];
  mm[0] = 1.f; mm[1] = c1; mm[2] = s1; mm[3] = c2; mm[4] = s2;
  mm[5] = c1 * c2; mm[6] = c1 * s2; mm[7] = s1 * c2; mm[8] = s1 * s2;
  float P[3];
#pragma unroll
  for (int p = 0; p < 3; ++p) {
    const float* tt = tb + p * 9;
    float acc = tt[0];
#pragma unroll
    for (int i = 1; i < 9; ++i) acc = fmaf(tt[i], mm[i], acc);
    P[p] = acc;
  }
  return fmaf(s0, P[2], fmaf(c0, P[1], P[0]));
}

// block = 512 threads = 8 waves; lane b = batch elem (64/block); wave ws owns
// k-blocks {4ws..4ws+3}. One LDS buffer [64][97] in CONSUMER-ORDER slots:
// slot 3k+j of row b holds the value block k, wire j will read next layer.
__global__ __launch_bounds__(512, 8) void vqc_main(const float* __restrict__ x,
                                                   const float* __restrict__ T,
                                                   const hf2* __restrict__ Th,
                                                   const float* __restrict__ wcls,
                                                   const float* __restrict__ bcls,
                                                   float* __restrict__ out) {
  __shared__ float buf[64 * STRIDE];  // 24832 B
  const int t = threadIdx.x;
  const int b0 = blockIdx.x * 64;

  // stage x (coalesced float4 reads) into buf, natural order
  const float4* xv = (const float4*)(x + (size_t)b0 * 96);
#pragma unroll
  for (int i = 0; i < 3; ++i) {
    float4 v = xv[t + i * 512];
    int idx = (t + i * 512) * 4;
    int row = idx / 96, col = idx % 96;
    float* p = &buf[row * STRIDE + col];
    p[0] = v.x; p[1] = v.y; p[2] = v.z; p[3] = v.w;
  }

  const int b = t & 63;                                   // batch within block
  const int ws = __builtin_amdgcn_readfirstlane(t >> 6);  // wave id 0..7 (scalar)
  const int rbase = b * STRIDE + 12 * ws;                 // contiguous read base
  __syncthreads();

  float h[4][3];
  float xin[12];

  // ---- layer 0 (stem): natural order == consumer order for stem inputs ----
#pragma unroll
  for (int i = 0; i < 12; ++i) xin[i] = buf[rbase + i];
  __syncthreads();  // all reads of x done before consumer-order overwrite
#pragma unroll
  for (int kk = 0; kk < 4; ++kk) {
    int k = ws * 4 + kk;
    float s0, c0, s1, c1, s2, c2;
    fast_sincos(xin[3 * kk + 0], s0, c0);
    fast_sincos(xin[3 * kk + 1], s1, c1);
    fast_sincos(xin[3 * kk + 2], s2, c2);
    float z[3];
    q3eval_h(s0, c0, s1, c1, s2, c2, Th + (size_t)k * 45, z);
#pragma unroll
    for (int j = 0; j < 3; ++j) h[kk][j] = z[j];
  }
  // consumer-order writes: slot 32j + k (4 consecutive slots per j -> write2)
#pragma unroll
  for (int j = 0; j < 3; ++j)
#pragma unroll
    for (int kk = 0; kk < 4; ++kk)
      buf[b * STRIDE + 32 * j + 4 * ws + kk] = h[kk][j];
  __syncthreads();

  // ---- layers 1..4: contiguous reads, residual in regs ----
  for (int l = 1; l < 5; ++l) {
#pragma unroll
    for (int i = 0; i < 12; ++i) xin[i] = buf[rbase + i];
    __syncthreads();  // all reads of H_{l-1} done
#pragma unroll
    for (int kk = 0; kk < 4; ++kk) {
      int k = ws * 4 + kk;
      float s0, c0, s1, c1, s2, c2;
      fast_sincos(xin[3 * kk + 0], s0, c0);
      fast_sincos(xin[3 * kk + 1], s1, c1);
      fast_sincos(xin[3 * kk + 2], s2, c2);
      float z[3];
      q3eval_h(s0, c0, s1, c1, s2, c2, Th + (size_t)(l * 32 + k) * 45, z);
#pragma unroll
      for (int j = 0; j < 3; ++j) h[kk][j] += z[j];
    }
    if (l < 4) {
#pragma unroll
      for (int j = 0; j < 3; ++j)
#pragma unroll
        for (int kk = 0; kk < 4; ++kk)
          buf[b * STRIDE + 32 * j + 4 * ws + kk] = h[kk][j];
      __syncthreads();  // writes visible before next layer's reads
    }
  }

  // ---- layer 5 (reduce, wire 0): inputs = own regs; f32 path ----
#pragma unroll
  for (int kk = 0; kk < 4; ++kk) {
    int k = ws * 4 + kk;
    float s0, c0, s1, c1, s2, c2;
    fast_sincos(h[kk][0], s0, c0);
    fast_sincos(h[kk][1], s1, c1);
    fast_sincos(h[kk][2], s2, c2);
    float z = q3eval1_f(s0, c0, s1, c1, s2, c2, T + (size_t)(5 * 32 + k) * 81);
    buf[b * STRIDE + k] = z;  // safe: layer-4 gathers done at last barrier
  }
  __syncthreads();

  // classifier: out[b][c] = sum_k z[b][k] * wcls[c][k] + bcls[c]
  for (int idx = t; idx < 640; idx += 512) {
    int bb = idx / 10, c = idx % 10;
    float acc = bcls[c];
#pragma unroll
    for (int k = 0; k < 32; ++k)
      acc = fmaf(buf[bb * STRIDE + k], wcls[c * 32 + k], acc);
    out[(size_t)(b0 + bb) * 10 + c] = acc;
  }
}

extern "C" void kernel_launch(void* const* d_in, const int* in_sizes, int n_in,
                              void* d_out, int out_size, void* d_ws, size_t ws_size,
                              hipStream_t stream) {
  const float* x  = (const float*)d_in[0];   // (65536, 96) f32
  const float* th = (const float*)d_in[1];   // (6,32,6,3,3) f32
  const float* wc = (const float*)d_in[2];   // (10,32) f32
  const float* bc = (const float*)d_in[3];   // (10,) f32
  float* out = (float*)d_out;                // (65536,10) f32
  float* T = (float*)d_ws;                   // 6*32*81 = 15552 f32 (62 KB)
  hf2* Th = (hf2*)(T + 15552);               // 6*32*45 = 8640 hf2 (34.6 KB)

  build_T<<<6, 256, 0, stream>>>(th, T, Th);
  vqc_main<<<65536 / 64, 512, 0, stream>>>(x, T, Th, wc, bc, out);
}